// Round 3
// baseline (383.124 us; speedup 1.0000x reference)
//
#include <hip/hip_runtime.h>

typedef unsigned short u16;
typedef unsigned int u32;
typedef short bf16x8 __attribute__((ext_vector_type(8)));
typedef float f32x4 __attribute__((ext_vector_type(4)));

#define CSC 0.18033688011112042f   // (1/8) * log2(e)

// ---------- bf16 helpers (RNE) ----------
__device__ __forceinline__ u16 f2bf(float f) {
    union { float f; unsigned u; } x; x.f = f;
    unsigned r = x.u + 0x7fffu + ((x.u >> 16) & 1u);
    return (u16)(r >> 16);
}
__device__ __forceinline__ float bf2f(u16 v) {
    union { unsigned u; float f; } x; x.u = ((unsigned)v) << 16;
    return x.f;
}
__device__ __forceinline__ float exp2_fast(float x) {
#if __has_builtin(__builtin_amdgcn_exp2f)
    return __builtin_amdgcn_exp2f(x);
#else
    return exp2f(x);
#endif
}
__device__ __forceinline__ void gl_lds16(const u16* g, u16* l) {
#if __has_builtin(__builtin_amdgcn_global_load_lds)
    __builtin_amdgcn_global_load_lds(
        (const __attribute__((address_space(1))) unsigned int*)g,
        (__attribute__((address_space(3))) unsigned int*)l, 16, 0, 0);
#else
    *(bf16x8*)l = *(const bf16x8*)g;
#endif
}

// ---------- fp32 -> bf16: x ----------
__global__ void cvt_x_kernel(const float* __restrict__ in, u16* __restrict__ out, int n4) {
    int i = blockIdx.x * blockDim.x + threadIdx.x;
    if (i < n4) {
        float4 v = ((const float4*)in)[i];
        ushort4 o;
        o.x = f2bf(v.x); o.y = f2bf(v.y); o.z = f2bf(v.z); o.w = f2bf(v.w);
        ((ushort4*)out)[i] = o;
    }
}

// ---------- fp32 -> bf16: all 4 weights (wq|wk|wv -> qkvw concat, wo -> ow) ----------
__global__ void cvt_w_kernel(const float* __restrict__ wq, const float* __restrict__ wk,
                             const float* __restrict__ wv, const float* __restrict__ wo,
                             u16* __restrict__ qkvw, u16* __restrict__ ow) {
    int i = blockIdx.x * 256 + threadIdx.x;       // 0..262143 (float4 index per matrix)
    int m = blockIdx.y;
    const float* src = (m == 0) ? wq : (m == 1) ? wk : (m == 2) ? wv : wo;
    u16* dst = (m < 3) ? (qkvw + (size_t)m * 1048576) : ow;
    float4 v = ((const float4*)src)[i];
    ushort4 o;
    o.x = f2bf(v.x); o.y = f2bf(v.y); o.z = f2bf(v.z); o.w = f2bf(v.w);
    ((ushort4*)dst)[i] = o;
}

// ---------- RoPE in-place on both q and k [BH,S,64] bf16 ----------
__global__ void rope_kernel(u16* __restrict__ qb, u16* __restrict__ kb) {
    int idx = blockIdx.x * 256 + threadIdx.x;     // 2M threads per buffer
    u16* buf = blockIdx.y ? kb : qb;
    int i = idx & 31;
    int s = (idx >> 5) & 2047;
    float inv = exp2_fast((float)i * -0.4152410118609203f);  // 10000^(-i/32)
    float ang = (float)s * inv;
    float sn, cs;
    sincosf(ang, &sn, &cs);
    u16* p = buf + (size_t)(idx >> 5) * 64 + 2 * i;
    float e = bf2f(p[0]);
    float o = bf2f(p[1]);
    p[0] = f2bf(e * cs - o * sn);
    p[1] = f2bf(o * cs + e * sn);
}

// ---------- m97-structure GEMM: 128x128 tile, BK=32, C = A * Bw^T ----------
// MODE 0: QKV epilogue. N=3072: n<1024 -> q[B,H,S,64]; <2048 -> k; <3072 -> v^T
//         [B,H,64,S] with per-32-chunk key interleave perm (for attn packed P).
// MODE 1: fp32 row-major [M,1024].
template<int MODE>
__global__ __launch_bounds__(256) void gemm128(const u16* __restrict__ A,
                                               const u16* __restrict__ Bw,
                                               void* __restrict__ C, int K) {
    __shared__ __align__(16) u16 As[128 * 32];
    __shared__ __align__(16) u16 Bs[128 * 32];
    const int tid  = threadIdx.x;
    const int bm   = blockIdx.x * 128;
    const int bn   = blockIdx.y * 128;
    const int wave = tid >> 6, lane = tid & 63;
    const int wm   = (wave >> 1) * 64, wn = (wave & 1) * 64;
    const int l16  = lane & 15, quad = lane >> 4;

    f32x4 acc[4][4];
    #pragma unroll
    for (int i = 0; i < 4; i++)
        #pragma unroll
        for (int j = 0; j < 4; j++)
            #pragma unroll
            for (int e = 0; e < 4; e++) acc[i][j][e] = 0.0f;

    const int srow = tid >> 2, scol = (tid & 3) * 8;
    const u16* gA0 = A  + (size_t)(bm + srow) * K + scol;
    const u16* gA1 = A  + (size_t)(bm + 64 + srow) * K + scol;
    const u16* gB0 = Bw + (size_t)(bn + srow) * K + scol;
    const u16* gB1 = Bw + (size_t)(bn + 64 + srow) * K + scol;
    u16* lA0 = &As[(size_t)tid * 8];
    u16* lA1 = &As[(size_t)(tid + 256) * 8];
    u16* lB0 = &Bs[(size_t)tid * 8];
    u16* lB1 = &Bs[(size_t)(tid + 256) * 8];

    for (int k0 = 0; k0 < K; k0 += 32) {
        __syncthreads();
        gl_lds16(gA0 + k0, lA0);
        gl_lds16(gA1 + k0, lA1);
        gl_lds16(gB0 + k0, lB0);
        gl_lds16(gB1 + k0, lB1);
        __syncthreads();
        bf16x8 af[4], bfr[4];
        #pragma unroll
        for (int i = 0; i < 4; i++) af[i]  = *(const bf16x8*)&As[(wm + i * 16 + l16) * 32 + quad * 8];
        #pragma unroll
        for (int j = 0; j < 4; j++) bfr[j] = *(const bf16x8*)&Bs[(wn + j * 16 + l16) * 32 + quad * 8];
        #pragma unroll
        for (int i = 0; i < 4; i++)
            #pragma unroll
            for (int j = 0; j < 4; j++)
                acc[i][j] = __builtin_amdgcn_mfma_f32_16x16x32_bf16(af[i], bfr[j], acc[i][j], 0, 0, 0);
    }

    #pragma unroll
    for (int i = 0; i < 4; i++) {
        #pragma unroll
        for (int j = 0; j < 4; j++) {
            #pragma unroll
            for (int r = 0; r < 4; r++) {
                int mr = bm + wm + i * 16 + quad * 4 + r;   // C/D: row = quad*4+reg
                int nc = bn + wn + j * 16 + l16;            //      col = lane&15
                float v = acc[i][j][r];
                if (MODE == 0) {
                    int mat = nc >> 10;                     // block-uniform (1024%128==0)
                    int c   = nc & 1023;
                    int b = mr >> 11, s = mr & 2047, h = c >> 6, dv = c & 63;
                    u16* out = (u16*)C;
                    if (mat == 0) {
                        out[(((size_t)(b * 16 + h) * 2048 + s) * 64) + dv] = f2bf(v);
                    } else if (mat == 1) {
                        out[(size_t)4194304 + (((size_t)(b * 16 + h) * 2048 + s) * 64) + dv] = f2bf(v);
                    } else {
                        // v^T with key interleave: within 32-chunk, real c32 -> stored
                        int c32 = s & 31;
                        int st  = (c32 < 16) ? (2 * c32) : (2 * (c32 - 16) + 1);
                        int sp  = (s & ~31) + st;
                        out[(size_t)8388608 + (((size_t)(b * 16 + h) * 64 + dv) * 2048) + sp] = f2bf(v);
                    }
                } else {
                    ((float*)C)[(size_t)mr * 1024 + nc] = v;
                }
            }
        }
    }
}

// ---------- Flash attention: 1 wave = 16 queries, longest-first dispatch ----------
// grid (32, 32): qt = 31-blockIdx.x (long blocks first), bh = blockIdx.y.
// Fixed-max softmax (|s/8| < 0.2, no overflow), packed-u32 P through padded LDS,
// V^T pre-permuted so PV B-frag reads are contiguous b128. No block barriers.
__global__ __launch_bounds__(256, 4) void attn_kernel(const u16* __restrict__ Q,
                                                      const u16* __restrict__ Kb,
                                                      const u16* __restrict__ Vt,
                                                      u16* __restrict__ Oout) {
    __shared__ __align__(16) u16 Plds[4][16 * 40];   // row stride 40 u16 (2-way banks, free)
    const int tid  = threadIdx.x;
    const int wave = tid >> 6, lane = tid & 63;
    const int l16  = lane & 15, quad = lane >> 4;
    const int qt   = 31 - blockIdx.x;
    const int bh   = blockIdx.y;
    const int q0   = qt * 64 + wave * 16;

    const u16* Qh = Q  + (size_t)bh * 2048 * 64;
    const u16* Kh = Kb + (size_t)bh * 2048 * 64;
    const u16* Vh = Vt + (size_t)bh * 64 * 2048;

    bf16x8 qf0 = *(const bf16x8*)&Qh[(size_t)(q0 + l16) * 64 + quad * 8];
    bf16x8 qf1 = *(const bf16x8*)&Qh[(size_t)(q0 + l16) * 64 + 32 + quad * 8];

    f32x4 o[4];
    float ls[4];
    #pragma unroll
    for (int t = 0; t < 4; t++)
        #pragma unroll
        for (int e = 0; e < 4; e++) o[t][e] = 0.0f;
    #pragma unroll
    for (int r = 0; r < 4; r++) ls[r] = 0.0f;

    const int ktW = (q0 + 15) >> 5;   // inclusive last key tile
    u16* pl  = Plds[wave];
    u32* plw = (u32*)pl;

    auto loadK = [&](int kt, bf16x8* kd) {
        const int kbase = kt * 32;
        kd[0] = *(const bf16x8*)&Kh[(size_t)(kbase + l16) * 64 + quad * 8];
        kd[1] = *(const bf16x8*)&Kh[(size_t)(kbase + l16) * 64 + 32 + quad * 8];
        kd[2] = *(const bf16x8*)&Kh[(size_t)(kbase + 16 + l16) * 64 + quad * 8];
        kd[3] = *(const bf16x8*)&Kh[(size_t)(kbase + 16 + l16) * 64 + 32 + quad * 8];
    };

    auto step = [&](int kt, bf16x8* kc) {
        const int kbase = kt * 32;
        bf16x8 vc[4];                                   // issue V loads first; QK+exp hides latency
        #pragma unroll
        for (int t = 0; t < 4; t++)
            vc[t] = *(const bf16x8*)&Vh[(size_t)(t * 16 + l16) * 2048 + kbase + quad * 8];
        f32x4 s0 = {0.f, 0.f, 0.f, 0.f}, s1 = {0.f, 0.f, 0.f, 0.f};
        s0 = __builtin_amdgcn_mfma_f32_16x16x32_bf16(qf0, kc[0], s0, 0, 0, 0);
        s0 = __builtin_amdgcn_mfma_f32_16x16x32_bf16(qf1, kc[1], s0, 0, 0, 0);
        s1 = __builtin_amdgcn_mfma_f32_16x16x32_bf16(qf0, kc[2], s1, 0, 0, 0);
        s1 = __builtin_amdgcn_mfma_f32_16x16x32_bf16(qf1, kc[3], s1, 0, 0, 0);
        const bool mask = (kt == ktW);
        #pragma unroll
        for (int r = 0; r < 4; r++) {
            float p0 = exp2_fast(s0[r] * CSC);          // key kbase+l16
            float p1 = exp2_fast(s1[r] * CSC);          // key kbase+16+l16
            if (mask) {
                int row = q0 + quad * 4 + r;
                p0 = (kbase + l16      > row) ? 0.0f : p0;
                p1 = (kbase + 16 + l16 > row) ? 0.0f : p1;
            }
            ls[r] += p0 + p1;
            // stored keys [2*l16, 2*l16+1] <-> real [kbase+l16, kbase+16+l16] (= V perm)
            plw[(quad * 4 + r) * 20 + l16] = (u32)f2bf(p0) | ((u32)f2bf(p1) << 16);
        }
        asm volatile("s_waitcnt lgkmcnt(0)" ::: "memory");   // wave-local drain
        bf16x8 pf = *(const bf16x8*)&pl[l16 * 40 + quad * 8];
        #pragma unroll
        for (int t = 0; t < 4; t++)
            o[t] = __builtin_amdgcn_mfma_f32_16x16x32_bf16(pf, vc[t], o[t], 0, 0, 0);
    };

    bf16x8 k0r[4], k1r[4];
    loadK(0, k0r);
    int kt = 0;
    while (true) {
        if (kt < ktW) loadK(kt + 1, k1r);
        step(kt, k0r);
        if (++kt > ktW) break;
        if (kt < ktW) loadK(kt + 1, k0r);
        step(kt, k1r);
        if (++kt > ktW) break;
    }

    #pragma unroll
    for (int off = 1; off < 16; off <<= 1)
        #pragma unroll
        for (int r = 0; r < 4; r++) ls[r] += __shfl_xor(ls[r], off);

    const int b = bh >> 4, h = bh & 15;
    #pragma unroll
    for (int r = 0; r < 4; r++) {
        float inv = 1.0f / ls[r];
        int s = q0 + quad * 4 + r;
        #pragma unroll
        for (int t = 0; t < 4; t++) {
            int d = h * 64 + t * 16 + l16;
            Oout[((size_t)b * 2048 + s) * 1024 + d] = f2bf(o[t][r] * inv);
        }
    }
}

extern "C" void kernel_launch(void* const* d_in, const int* in_sizes, int n_in,
                              void* d_out, int out_size, void* d_ws, size_t ws_size,
                              hipStream_t stream) {
    const float* x  = (const float*)d_in[0];
    const float* wq = (const float*)d_in[1];
    const float* wk = (const float*)d_in[2];
    const float* wv = (const float*)d_in[3];
    const float* wo = (const float*)d_in[4];
    float* out = (float*)d_out;

    const int M = 4096, D = 1024;
    u16* xb    = (u16*)d_ws;                      // [4096,1024]            8 MB
    u16* qkvw  = xb   + (size_t)M * D;            // [3072,1024] wq|wk|wv   6 MB
    u16* ow    = qkvw + (size_t)3 * D * D;        // [1024,1024]            2 MB
    u16* qkv   = ow   + (size_t)D * D;            // q[BH,S,64] k[...] v^T[BH,64,S]  24 MB
    u16* qb    = qkv;
    u16* kb    = qkv + (size_t)M * D;
    u16* vtb   = qkv + (size_t)2 * M * D;
    u16* aob   = qkv + (size_t)3 * M * D;         // attn out bf16 [B,S,D]  8 MB

    cvt_x_kernel<<<(M * D / 4 + 255) / 256, 256, 0, stream>>>(x, xb, M * D / 4);
    dim3 gw(D * D / 4 / 256, 4);
    cvt_w_kernel<<<gw, 256, 0, stream>>>(wq, wk, wv, wo, qkvw, ow);

    dim3 gq(32, 24);                               // 768 blocks = 3/CU
    gemm128<0><<<gq, 256, 0, stream>>>(xb, qkvw, qkv, D);

    dim3 gr(32 * 2048 * 32 / 256, 2);
    rope_kernel<<<gr, 256, 0, stream>>>(qb, kb);

    dim3 ga(32, 32);                               // 1024 blocks, longest-first
    attn_kernel<<<ga, 256, 0, stream>>>(qb, kb, vtb, aob);

    dim3 go(32, 8);
    gemm128<1><<<go, 256, 0, stream>>>(aob, ow, out, D);
}

// Round 4
// 199.470 us; speedup vs baseline: 1.9207x; 1.9207x over previous
//
#include <hip/hip_runtime.h>

typedef unsigned short u16;
typedef unsigned int u32;
typedef short bf16x8 __attribute__((ext_vector_type(8)));
typedef float f32x4 __attribute__((ext_vector_type(4)));

#define CSC 0.18033688011112042f   // (1/8) * log2(e)

// ---------- bf16 helpers (RNE) ----------
__device__ __forceinline__ u16 f2bf(float f) {
    union { float f; unsigned u; } x; x.f = f;
    unsigned r = x.u + 0x7fffu + ((x.u >> 16) & 1u);
    return (u16)(r >> 16);
}
__device__ __forceinline__ float bf2f(u16 v) {
    union { unsigned u; float f; } x; x.u = ((unsigned)v) << 16;
    return x.f;
}
__device__ __forceinline__ float exp2_fast(float x) {
#if __has_builtin(__builtin_amdgcn_exp2f)
    return __builtin_amdgcn_exp2f(x);
#else
    return exp2f(x);
#endif
}
__device__ __forceinline__ void gl_lds16(const u16* g, u16* l) {
#if __has_builtin(__builtin_amdgcn_global_load_lds)
    __builtin_amdgcn_global_load_lds(
        (const __attribute__((address_space(1))) unsigned int*)g,
        (__attribute__((address_space(3))) unsigned int*)l, 16, 0, 0);
#else
    *(bf16x8*)l = *(const bf16x8*)g;
#endif
}
__device__ __forceinline__ int ileave(int x) {   // per-32 stored-key interleave
    return (x < 16) ? (x << 1) : (((x - 16) << 1) | 1);
}

// ---------- fp32 -> bf16: x ----------
__global__ void cvt_x_kernel(const float* __restrict__ in, u16* __restrict__ out, int n4) {
    int i = blockIdx.x * blockDim.x + threadIdx.x;
    if (i < n4) {
        float4 v = ((const float4*)in)[i];
        ushort4 o;
        o.x = f2bf(v.x); o.y = f2bf(v.y); o.z = f2bf(v.z); o.w = f2bf(v.w);
        ((ushort4*)out)[i] = o;
    }
}

// ---------- fp32 -> bf16: weights (wq|wk|wv -> qkvw, wo -> ow) ----------
__global__ void cvt_w_kernel(const float* __restrict__ wq, const float* __restrict__ wk,
                             const float* __restrict__ wv, const float* __restrict__ wo,
                             u16* __restrict__ qkvw, u16* __restrict__ ow) {
    int i = blockIdx.x * 256 + threadIdx.x;
    int m = blockIdx.y;
    const float* src = (m == 0) ? wq : (m == 1) ? wk : (m == 2) ? wv : wo;
    u16* dst = (m < 3) ? (qkvw + (size_t)m * 1048576) : ow;
    float4 v = ((const float4*)src)[i];
    ushort4 o;
    o.x = f2bf(v.x); o.y = f2bf(v.y); o.z = f2bf(v.z); o.w = f2bf(v.w);
    ((ushort4*)dst)[i] = o;
}

// ---------- RoPE in-place on q and k [BH,S,64] bf16 ----------
__global__ void rope_kernel(u16* __restrict__ qb, u16* __restrict__ kb) {
    int idx = blockIdx.x * 256 + threadIdx.x;
    u16* buf = blockIdx.y ? kb : qb;
    int i = idx & 31;
    int s = (idx >> 5) & 2047;
    float inv = exp2_fast((float)i * -0.4152410118609203f);  // 10000^(-i/32)
    float ang = (float)s * inv;
    float sn, cs;
    sincosf(ang, &sn, &cs);
    u16* p = buf + (size_t)(idx >> 5) * 64 + 2 * i;
    float e = bf2f(p[0]);
    float o = bf2f(p[1]);
    p[0] = f2bf(e * cs - o * sn);
    p[1] = f2bf(o * cs + e * sn);
}

// ---------- QKV GEMM: 128x128 tile, BK=32, C = A * Bw^T, N=3072 ----------
// n<1024 -> q[B,H,S,64]; <2048 -> k; <3072 -> v^T [B,H,64,S] (stored-key
// interleave, written via LDS transpose for coalescing).
__global__ __launch_bounds__(256) void gemm_qkv(const u16* __restrict__ A,
                                                const u16* __restrict__ Bw,
                                                u16* __restrict__ C, int K) {
    __shared__ __align__(16) u16 SH[8192];       // As = SH[0:4096], Bs = SH[4096:8192]
    u16* As = SH;
    u16* Bs = SH + 4096;
    const int tid  = threadIdx.x;
    const int bm   = blockIdx.x * 128;
    const int bn   = blockIdx.y * 128;
    const int wave = tid >> 6, lane = tid & 63;
    const int wm   = (wave >> 1) * 64, wn = (wave & 1) * 64;
    const int l16  = lane & 15, quad = lane >> 4;
    const int mat  = bn >> 10;                   // block-uniform

    f32x4 acc[4][4];
    #pragma unroll
    for (int i = 0; i < 4; i++)
        #pragma unroll
        for (int j = 0; j < 4; j++)
            #pragma unroll
            for (int e = 0; e < 4; e++) acc[i][j][e] = 0.0f;

    const int srow = tid >> 2, scol = (tid & 3) * 8;
    const u16* gA0 = A  + (size_t)(bm + srow) * K + scol;
    const u16* gA1 = A  + (size_t)(bm + 64 + srow) * K + scol;
    const u16* gB0 = Bw + (size_t)(bn + srow) * K + scol;
    const u16* gB1 = Bw + (size_t)(bn + 64 + srow) * K + scol;
    u16* lA0 = &As[(size_t)tid * 8];
    u16* lA1 = &As[(size_t)(tid + 256) * 8];
    u16* lB0 = &Bs[(size_t)tid * 8];
    u16* lB1 = &Bs[(size_t)(tid + 256) * 8];

    for (int k0 = 0; k0 < K; k0 += 32) {
        __syncthreads();
        gl_lds16(gA0 + k0, lA0);
        gl_lds16(gA1 + k0, lA1);
        gl_lds16(gB0 + k0, lB0);
        gl_lds16(gB1 + k0, lB1);
        __syncthreads();
        bf16x8 af[4], bfr[4];
        #pragma unroll
        for (int i = 0; i < 4; i++) af[i]  = *(const bf16x8*)&As[(wm + i * 16 + l16) * 32 + quad * 8];
        #pragma unroll
        for (int j = 0; j < 4; j++) bfr[j] = *(const bf16x8*)&Bs[(wn + j * 16 + l16) * 32 + quad * 8];
        #pragma unroll
        for (int i = 0; i < 4; i++)
            #pragma unroll
            for (int j = 0; j < 4; j++)
                acc[i][j] = __builtin_amdgcn_mfma_f32_16x16x32_bf16(af[i], bfr[j], acc[i][j], 0, 0, 0);
    }

    if (mat < 2) {
        #pragma unroll
        for (int i = 0; i < 4; i++)
            #pragma unroll
            for (int j = 0; j < 4; j++)
                #pragma unroll
                for (int r = 0; r < 4; r++) {
                    int mr = bm + wm + i * 16 + quad * 4 + r;
                    int nc = bn + wn + j * 16 + l16;
                    int c = nc & 1023;
                    int b = mr >> 11, s = mr & 2047, h = c >> 6, dv = c & 63;
                    C[(size_t)mat * 4194304 + (((size_t)(b * 16 + h) * 2048 + s) * 64) + dv] =
                        f2bf(acc[i][j][r]);
                }
    } else {
        // v^T via LDS transpose: two 64-col passes through SH[64][128]
        const int b  = bm >> 11, sb = bm & 2047;
        #pragma unroll
        for (int pass = 0; pass < 2; ++pass) {
            __syncthreads();
            if ((wn >> 6) == pass) {
                #pragma unroll
                for (int i = 0; i < 4; i++)
                    #pragma unroll
                    for (int j = 0; j < 4; j++)
                        #pragma unroll
                        for (int r = 0; r < 4; r++) {
                            int row = j * 16 + l16;                      // ncl - pass*64
                            int ml  = wm + i * 16 + quad * 4 + r;
                            int sp  = (ml & ~31) | ileave(ml & 31);
                            SH[row * 128 + sp] = f2bf(acc[i][j][r]);
                        }
            }
            __syncthreads();
            int row = tid >> 2, seg = tid & 3;
            int cc  = (bn + pass * 64 + row) & 1023;
            int h = cc >> 6, dv = cc & 63;
            u16* dst = C + (size_t)8388608 +
                       (((size_t)(b * 16 + h) * 64 + dv) * 2048) + sb + seg * 32;
            const u16* srcp = &SH[row * 128 + seg * 32];
            #pragma unroll
            for (int kk = 0; kk < 4; ++kk)
                *(bf16x8*)(dst + kk * 8) = *(const bf16x8*)(srcp + kk * 8);
        }
    }
}

// ---------- O-proj GEMM: 128x64 tile, BK=32, fp32 out [M,1024] ----------
__global__ __launch_bounds__(256, 2) void gemm_out(const u16* __restrict__ A,
                                                   const u16* __restrict__ Bw,
                                                   float* __restrict__ C, int K) {
    __shared__ __align__(16) u16 As[128 * 32];
    __shared__ __align__(16) u16 Bs[64 * 32];
    const int tid  = threadIdx.x;
    const int bm   = blockIdx.x * 128;
    const int bn   = blockIdx.y * 64;
    const int wave = tid >> 6, lane = tid & 63;
    const int wm   = wave * 32;
    const int l16  = lane & 15, quad = lane >> 4;

    f32x4 acc[2][4];
    #pragma unroll
    for (int i = 0; i < 2; i++)
        #pragma unroll
        for (int j = 0; j < 4; j++)
            #pragma unroll
            for (int e = 0; e < 4; e++) acc[i][j][e] = 0.0f;

    const int srow = tid >> 2, scol = (tid & 3) * 8;
    const u16* gA0 = A  + (size_t)(bm + srow) * K + scol;
    const u16* gA1 = A  + (size_t)(bm + 64 + srow) * K + scol;
    const u16* gB0 = Bw + (size_t)(bn + srow) * K + scol;
    u16* lA0 = &As[(size_t)tid * 8];
    u16* lA1 = &As[(size_t)(tid + 256) * 8];
    u16* lB0 = &Bs[(size_t)tid * 8];

    for (int k0 = 0; k0 < K; k0 += 32) {
        __syncthreads();
        gl_lds16(gA0 + k0, lA0);
        gl_lds16(gA1 + k0, lA1);
        gl_lds16(gB0 + k0, lB0);
        __syncthreads();
        bf16x8 af[2], bfr[4];
        #pragma unroll
        for (int i = 0; i < 2; i++) af[i]  = *(const bf16x8*)&As[(wm + i * 16 + l16) * 32 + quad * 8];
        #pragma unroll
        for (int j = 0; j < 4; j++) bfr[j] = *(const bf16x8*)&Bs[(j * 16 + l16) * 32 + quad * 8];
        #pragma unroll
        for (int i = 0; i < 2; i++)
            #pragma unroll
            for (int j = 0; j < 4; j++)
                acc[i][j] = __builtin_amdgcn_mfma_f32_16x16x32_bf16(af[i], bfr[j], acc[i][j], 0, 0, 0);
    }

    #pragma unroll
    for (int i = 0; i < 2; i++)
        #pragma unroll
        for (int j = 0; j < 4; j++)
            #pragma unroll
            for (int r = 0; r < 4; r++) {
                int mr = bm + wm + i * 16 + quad * 4 + r;
                int nc = bn + j * 16 + l16;
                C[(size_t)mr * 1024 + nc] = acc[i][j][r];
            }
}

// ---------- Flash attention: paired q-tiles, LDS-staged K/V shared by block ----------
// grid (16, 32): j = pair index (q-tiles j and 31-j), bh. 4 waves; wave w owns
// 16 q of each side. Key tile 64, staged lo/hi into stride-32 LDS (m97 read
// pattern). Every wave does exactly 33 tile-computes. Fixed-max softmax.
__global__ __launch_bounds__(256, 2) void attn_kernel(const u16* __restrict__ Q,
                                                      const u16* __restrict__ Kb,
                                                      const u16* __restrict__ Vt,
                                                      u16* __restrict__ Oout) {
    __shared__ __align__(16) u16 KV[8192];       // Klo|Khi|Vlo|Vhi, 2048 u16 each
    __shared__ __align__(16) u16 PW[4 * 1152];   // per-wave P: 16 rows x 72 u16
    const int tid  = threadIdx.x;
    const int wave = tid >> 6, lane = tid & 63;
    const int l16  = lane & 15, quad = lane >> 4;
    const int j    = blockIdx.x;                 // 0..15 (j=0 longest, dispatched first)
    const int bh   = blockIdx.y;
    const int T    = 32 - j;                     // staged key tiles 0..T-1
    const int qA0  = j * 64 + wave * 16;
    const int qB0  = (31 - j) * 64 + wave * 16;

    const u16* Qh = Q  + (size_t)bh * 2048 * 64;
    const u16* Kh = Kb + (size_t)bh * 2048 * 64;
    const u16* Vh = Vt + (size_t)bh * 64 * 2048;

    bf16x8 qAf0 = *(const bf16x8*)&Qh[(size_t)(qA0 + l16) * 64 + quad * 8];
    bf16x8 qAf1 = *(const bf16x8*)&Qh[(size_t)(qA0 + l16) * 64 + 32 + quad * 8];
    bf16x8 qBf0 = *(const bf16x8*)&Qh[(size_t)(qB0 + l16) * 64 + quad * 8];
    bf16x8 qBf1 = *(const bf16x8*)&Qh[(size_t)(qB0 + l16) * 64 + 32 + quad * 8];

    f32x4 oA[4], oB[4];
    float lsA[4], lsB[4];
    #pragma unroll
    for (int t = 0; t < 4; t++)
        #pragma unroll
        for (int e = 0; e < 4; e++) { oA[t][e] = 0.0f; oB[t][e] = 0.0f; }
    #pragma unroll
    for (int r = 0; r < 4; r++) { lsA[r] = 0.0f; lsB[r] = 0.0f; }

    // staging ptrs: thread tid handles 16B chunk tid of each 4KB array
    const int cch = tid;
    const u16* gK = Kh + (size_t)(cch >> 2) * 64 + (cch & 3) * 8;    // key=c>>2, dims (c&3)*8
    const u16* gV = Vh + (size_t)(cch >> 2) * 2048 + (cch & 3) * 8;  // dim=c>>2, keys (c&3)*8
    u16* lK0 = &KV[(size_t)cch * 8];
    u16* lK1 = &KV[2048 + (size_t)cch * 8];
    u16* lV0 = &KV[4096 + (size_t)cch * 8];
    u16* lV1 = &KV[6144 + (size_t)cch * 8];

    u16* pw16 = PW + wave * 1152;
    u32* pw32 = (u32*)pw16;

    auto side = [&](const bf16x8& q0f, const bf16x8& q1f, bf16x8* kf0, bf16x8* kf1,
                    bf16x8* vf0, bf16x8* vf1, f32x4* o, float* ls,
                    int q0, int kbase, bool diag) {
        f32x4 s[4];
        #pragma unroll
        for (int n = 0; n < 4; n++) {
            #pragma unroll
            for (int e = 0; e < 4; e++) s[n][e] = 0.0f;
            s[n] = __builtin_amdgcn_mfma_f32_16x16x32_bf16(q0f, kf0[n], s[n], 0, 0, 0);
            s[n] = __builtin_amdgcn_mfma_f32_16x16x32_bf16(q1f, kf1[n], s[n], 0, 0, 0);
        }
        float p[4][4];
        #pragma unroll
        for (int n = 0; n < 4; n++)
            #pragma unroll
            for (int r = 0; r < 4; r++) {
                float v = exp2_fast(s[n][r] * CSC);   // fixed max=0: |s/8|<0.2
                if (diag) {
                    int row = q0 + quad * 4 + r;
                    v = (kbase + n * 16 + l16 > row) ? 0.0f : v;
                }
                p[n][r] = v;
                ls[r] += v;
            }
        // pack keys (n=2c, n=2c+1) -> stored positions c*32 + 2*l16 (+1)
        #pragma unroll
        for (int c = 0; c < 2; c++)
            #pragma unroll
            for (int r = 0; r < 4; r++)
                pw32[(quad * 4 + r) * 36 + c * 16 + l16] =
                    (u32)f2bf(p[2 * c][r]) | ((u32)f2bf(p[2 * c + 1][r]) << 16);
        asm volatile("s_waitcnt lgkmcnt(0)" ::: "memory");   // wave-local drain
        bf16x8 pf0 = *(const bf16x8*)&pw16[l16 * 72 + quad * 8];
        bf16x8 pf1 = *(const bf16x8*)&pw16[l16 * 72 + 32 + quad * 8];
        #pragma unroll
        for (int dn = 0; dn < 4; dn++) {
            o[dn] = __builtin_amdgcn_mfma_f32_16x16x32_bf16(pf0, vf0[dn], o[dn], 0, 0, 0);
            o[dn] = __builtin_amdgcn_mfma_f32_16x16x32_bf16(pf1, vf1[dn], o[dn], 0, 0, 0);
        }
    };

    for (int t = 0; t < T; ++t) {
        __syncthreads();                          // previous compute done
        gl_lds16(gK + (size_t)t * 4096, lK0);
        gl_lds16(gK + (size_t)t * 4096 + 32, lK1);
        gl_lds16(gV + (size_t)t * 64, lV0);
        gl_lds16(gV + (size_t)t * 64 + 32, lV1);
        __syncthreads();                          // vmcnt drained by barrier

        bf16x8 kf0[4], kf1[4], vf0[4], vf1[4];
        #pragma unroll
        for (int n = 0; n < 4; n++) {
            int ri = (n * 16 + l16) * 32 + quad * 8;
            kf0[n] = *(const bf16x8*)&KV[ri];
            kf1[n] = *(const bf16x8*)&KV[2048 + ri];
            vf0[n] = *(const bf16x8*)&KV[4096 + ri];
            vf1[n] = *(const bf16x8*)&KV[6144 + ri];
        }
        const int kbase = t * 64;
        side(qBf0, qBf1, kf0, kf1, vf0, vf1, oB, lsB, qB0, kbase, t == T - 1);
        if (t <= j)
            side(qAf0, qAf1, kf0, kf1, vf0, vf1, oA, lsA, qA0, kbase, t == j);
    }

    #pragma unroll
    for (int off = 1; off < 16; off <<= 1)
        #pragma unroll
        for (int r = 0; r < 4; r++) {
            lsA[r] += __shfl_xor(lsA[r], off);
            lsB[r] += __shfl_xor(lsB[r], off);
        }

    const int b = bh >> 4, h = bh & 15;
    #pragma unroll
    for (int r = 0; r < 4; r++) {
        float iA = 1.0f / lsA[r];
        float iB = 1.0f / lsB[r];
        int sA = qA0 + quad * 4 + r;
        int sB = qB0 + quad * 4 + r;
        #pragma unroll
        for (int dn = 0; dn < 4; dn++) {
            int d = h * 64 + dn * 16 + l16;
            Oout[((size_t)b * 2048 + sA) * 1024 + d] = f2bf(oA[dn][r] * iA);
            Oout[((size_t)b * 2048 + sB) * 1024 + d] = f2bf(oB[dn][r] * iB);
        }
    }
}

extern "C" void kernel_launch(void* const* d_in, const int* in_sizes, int n_in,
                              void* d_out, int out_size, void* d_ws, size_t ws_size,
                              hipStream_t stream) {
    const float* x  = (const float*)d_in[0];
    const float* wq = (const float*)d_in[1];
    const float* wk = (const float*)d_in[2];
    const float* wv = (const float*)d_in[3];
    const float* wo = (const float*)d_in[4];
    float* out = (float*)d_out;

    const int M = 4096, D = 1024;
    u16* xb    = (u16*)d_ws;                      // [4096,1024]            8 MB
    u16* qkvw  = xb   + (size_t)M * D;            // wq|wk|wv bf16          6 MB
    u16* ow    = qkvw + (size_t)3 * D * D;        // wo bf16                2 MB
    u16* qkv   = ow   + (size_t)D * D;            // q | k | v^T            24 MB
    u16* qb    = qkv;
    u16* kb    = qkv + (size_t)M * D;
    u16* vtb   = qkv + (size_t)2 * M * D;
    u16* aob   = qkv + (size_t)3 * M * D;         // attn out bf16 [B,S,D]  8 MB

    cvt_x_kernel<<<(M * D / 4 + 255) / 256, 256, 0, stream>>>(x, xb, M * D / 4);
    dim3 gw(D * D / 4 / 256, 4);
    cvt_w_kernel<<<gw, 256, 0, stream>>>(wq, wk, wv, wo, qkvw, ow);

    dim3 gq(32, 24);                               // 768 blocks = 3/CU
    gemm_qkv<<<gq, 256, 0, stream>>>(xb, qkvw, qkv, D);

    dim3 gr(32 * 2048 * 32 / 256, 2);
    rope_kernel<<<gr, 256, 0, stream>>>(qb, kb);

    dim3 ga(16, 32);                               // 512 blocks, balanced pairs
    attn_kernel<<<ga, 256, 0, stream>>>(qb, kb, vtb, aob);

    dim3 go(32, 16);                               // 512 blocks, 128x64 tiles
    gemm_out<<<go, 256, 0, stream>>>(aob, ow, out, D);
}

// Round 5
// 198.912 us; speedup vs baseline: 1.9261x; 1.0028x over previous
//
#include <hip/hip_runtime.h>

typedef unsigned short u16;
typedef unsigned int u32;
typedef short bf16x8 __attribute__((ext_vector_type(8)));
typedef float f32x4 __attribute__((ext_vector_type(4)));

#define CSC 0.18033688011112042f   // (1/8) * log2(e)

// ---------- bf16 helpers (RNE) ----------
__device__ __forceinline__ u16 f2bf(float f) {
    union { float f; unsigned u; } x; x.f = f;
    unsigned r = x.u + 0x7fffu + ((x.u >> 16) & 1u);
    return (u16)(r >> 16);
}
__device__ __forceinline__ float bf2f(u16 v) {
    union { unsigned u; float f; } x; x.u = ((unsigned)v) << 16;
    return x.f;
}
__device__ __forceinline__ float exp2_fast(float x) {
#if __has_builtin(__builtin_amdgcn_exp2f)
    return __builtin_amdgcn_exp2f(x);
#else
    return exp2f(x);
#endif
}
__device__ __forceinline__ void gl_lds16(const u16* g, u16* l) {
#if __has_builtin(__builtin_amdgcn_global_load_lds)
    __builtin_amdgcn_global_load_lds(
        (const __attribute__((address_space(1))) unsigned int*)g,
        (__attribute__((address_space(3))) unsigned int*)l, 16, 0, 0);
#else
    *(bf16x8*)l = *(const bf16x8*)g;
#endif
}
__device__ __forceinline__ int ileave(int x) {   // per-32 stored-key interleave
    return (x < 16) ? (x << 1) : (((x - 16) << 1) | 1);
}

// ---------- fp32 -> bf16, all inputs in one launch ----------
// float4 index space: [0,1M) = x; then 4x 256K for wq,wk,wv,wo.
__global__ void cvt_all_kernel(const float* __restrict__ x, const float* __restrict__ wq,
                               const float* __restrict__ wk, const float* __restrict__ wv,
                               const float* __restrict__ wo,
                               u16* __restrict__ xb, u16* __restrict__ qkvw,
                               u16* __restrict__ ow) {
    int i = blockIdx.x * 256 + threadIdx.x;       // 0..2097151
    const float4* src;
    ushort4* dst;
    if (i < 1048576) {
        src = (const float4*)x + i;
        dst = (ushort4*)xb + i;
    } else {
        int r = i - 1048576;
        int m = r >> 18;
        int off = r & 262143;
        const float* s4 = (m == 0) ? wq : (m == 1) ? wk : (m == 2) ? wv : wo;
        u16* d = (m < 3) ? (qkvw + (size_t)m * 1048576) : ow;
        src = (const float4*)s4 + off;
        dst = (ushort4*)d + off;
    }
    float4 v = *src;
    ushort4 o;
    o.x = f2bf(v.x); o.y = f2bf(v.y); o.z = f2bf(v.z); o.w = f2bf(v.w);
    *dst = o;
}

// ---------- RoPE in-place, vectorized b128; q additionally pre-scaled by CSC ----------
__global__ void rope_kernel(u16* __restrict__ qb, u16* __restrict__ kb) {
    int idx = blockIdx.x * 256 + threadIdx.x;     // chunk of 8 u16; 524288 per buffer
    u16* buf;
    float scale;
    if (blockIdx.y == 0) { buf = qb; scale = CSC; } else { buf = kb; scale = 1.0f; }
    int g   = idx & 7;
    int row = idx >> 3;                           // bh*2048 + s
    int s   = row & 2047;
    u16* p = buf + (size_t)row * 64 + g * 8;
    bf16x8 v = *(bf16x8*)p;
    bf16x8 o;
    #pragma unroll
    for (int q = 0; q < 4; ++q) {
        int i = g * 4 + q;                        // pair index 0..31
        float inv = exp2_fast((float)i * -0.4152410118609203f);   // 10000^(-i/32)
        float ang = (float)s * inv;
        float sn, cs;
        sincosf(ang, &sn, &cs);
        float e  = bf2f(((u16*)&v)[2 * q]);
        float od = bf2f(((u16*)&v)[2 * q + 1]);
        ((u16*)&o)[2 * q]     = f2bf((e * cs - od * sn) * scale);
        ((u16*)&o)[2 * q + 1] = f2bf((od * cs + e * sn) * scale);
    }
    *(bf16x8*)p = o;
}

// ---------- QKV GEMM: 128x128 tile, BK=32, C = A * Bw^T, N=3072 ----------
// Epilogues route through padded LDS for conflict-free b128 global stores.
__global__ __launch_bounds__(256) void gemm_qkv(const u16* __restrict__ A,
                                                const u16* __restrict__ Bw,
                                                u16* __restrict__ C, int K) {
    __shared__ __align__(16) u16 SH[8448];       // staging: As=SH[0:4096], Bs=SH[4096:8192]
    u16* As = SH;
    u16* Bs = SH + 4096;
    const int tid  = threadIdx.x;
    const int bm   = blockIdx.x * 128;
    const int bn   = blockIdx.y * 128;
    const int wave = tid >> 6, lane = tid & 63;
    const int wm   = (wave >> 1) * 64, wn = (wave & 1) * 64;
    const int l16  = lane & 15, quad = lane >> 4;
    const int mat  = bn >> 10;                   // block-uniform (1024 % 128 == 0)

    f32x4 acc[4][4];
    #pragma unroll
    for (int i = 0; i < 4; i++)
        #pragma unroll
        for (int j = 0; j < 4; j++)
            #pragma unroll
            for (int e = 0; e < 4; e++) acc[i][j][e] = 0.0f;

    const int srow = tid >> 2, scol = (tid & 3) * 8;
    const u16* gA0 = A  + (size_t)(bm + srow) * K + scol;
    const u16* gA1 = A  + (size_t)(bm + 64 + srow) * K + scol;
    const u16* gB0 = Bw + (size_t)(bn + srow) * K + scol;
    const u16* gB1 = Bw + (size_t)(bn + 64 + srow) * K + scol;
    u16* lA0 = &As[(size_t)tid * 8];
    u16* lA1 = &As[(size_t)(tid + 256) * 8];
    u16* lB0 = &Bs[(size_t)tid * 8];
    u16* lB1 = &Bs[(size_t)(tid + 256) * 8];

    for (int k0 = 0; k0 < K; k0 += 32) {
        __syncthreads();
        gl_lds16(gA0 + k0, lA0);
        gl_lds16(gA1 + k0, lA1);
        gl_lds16(gB0 + k0, lB0);
        gl_lds16(gB1 + k0, lB1);
        __syncthreads();
        bf16x8 af[4], bfr[4];
        #pragma unroll
        for (int i = 0; i < 4; i++) af[i]  = *(const bf16x8*)&As[(wm + i * 16 + l16) * 32 + quad * 8];
        #pragma unroll
        for (int j = 0; j < 4; j++) bfr[j] = *(const bf16x8*)&Bs[(wn + j * 16 + l16) * 32 + quad * 8];
        #pragma unroll
        for (int i = 0; i < 4; i++)
            #pragma unroll
            for (int j = 0; j < 4; j++)
                acc[i][j] = __builtin_amdgcn_mfma_f32_16x16x32_bf16(af[i], bfr[j], acc[i][j], 0, 0, 0);
    }

    const int b  = bm >> 11, sb = bm & 2047;     // tile-uniform (2048 % 128 == 0)
    if (mat < 2) {
        // q/k: LDS transpose SH[128][66-stride], b128 stores, 2 passes of 64 cols
        #pragma unroll
        for (int pass = 0; pass < 2; ++pass) {
            __syncthreads();
            if ((wn >> 6) == pass) {
                #pragma unroll
                for (int i = 0; i < 4; i++)
                    #pragma unroll
                    for (int j = 0; j < 4; j++)
                        #pragma unroll
                        for (int r = 0; r < 4; r++) {
                            int rl = wm + i * 16 + quad * 4 + r;   // 0..127
                            int cl = j * 16 + l16;                 // 0..63
                            SH[rl * 66 + cl] = f2bf(acc[i][j][r]);
                        }
            }
            __syncthreads();
            int rl   = tid >> 1;
            int half = (tid & 1) * 32;
            int c    = (bn + pass * 64) & 1023;                    // dv base 0, h fixed
            int h    = c >> 6;
            int s    = sb + rl;
            u16* dst = C + (size_t)mat * 4194304 +
                       (((size_t)(b * 16 + h) * 2048 + s) * 64) + half;
            const u16* srcp = &SH[rl * 66 + half];
            #pragma unroll
            for (int kk = 0; kk < 4; ++kk)
                *(bf16x8*)(dst + kk * 8) = *(const bf16x8*)(srcp + kk * 8);
        }
    } else {
        // v^T: LDS transpose SH[64][130-stride] with stored-key interleave
        #pragma unroll
        for (int pass = 0; pass < 2; ++pass) {
            __syncthreads();
            if ((wn >> 6) == pass) {
                #pragma unroll
                for (int i = 0; i < 4; i++)
                    #pragma unroll
                    for (int j = 0; j < 4; j++)
                        #pragma unroll
                        for (int r = 0; r < 4; r++) {
                            int row = j * 16 + l16;                // 0..63 (dv local)
                            int ml  = wm + i * 16 + quad * 4 + r;  // 0..127 (key local)
                            int sp  = (ml & ~31) | ileave(ml & 31);
                            SH[row * 130 + sp] = f2bf(acc[i][j][r]);
                        }
            }
            __syncthreads();
            int row = tid >> 2, seg = tid & 3;
            int cc  = (bn + pass * 64 + row) & 1023;
            int h = cc >> 6, dv = cc & 63;
            u16* dst = C + (size_t)8388608 +
                       (((size_t)(b * 16 + h) * 64 + dv) * 2048) + sb + seg * 32;
            const u16* srcp = &SH[row * 130 + seg * 32];
            #pragma unroll
            for (int kk = 0; kk < 4; ++kk)
                *(bf16x8*)(dst + kk * 8) = *(const bf16x8*)(srcp + kk * 8);
        }
    }
}

// ---------- O-proj GEMM: 128x64 tile, BK=32, fp32 out [M,1024] ----------
__global__ __launch_bounds__(256, 2) void gemm_out(const u16* __restrict__ A,
                                                   const u16* __restrict__ Bw,
                                                   float* __restrict__ C, int K) {
    __shared__ __align__(16) u16 As[128 * 32];
    __shared__ __align__(16) u16 Bs[64 * 32];
    const int tid  = threadIdx.x;
    const int bm   = blockIdx.x * 128;
    const int bn   = blockIdx.y * 64;
    const int wave = tid >> 6, lane = tid & 63;
    const int wm   = wave * 32;
    const int l16  = lane & 15, quad = lane >> 4;

    f32x4 acc[2][4];
    #pragma unroll
    for (int i = 0; i < 2; i++)
        #pragma unroll
        for (int j = 0; j < 4; j++)
            #pragma unroll
            for (int e = 0; e < 4; e++) acc[i][j][e] = 0.0f;

    const int srow = tid >> 2, scol = (tid & 3) * 8;
    const u16* gA0 = A  + (size_t)(bm + srow) * K + scol;
    const u16* gA1 = A  + (size_t)(bm + 64 + srow) * K + scol;
    const u16* gB0 = Bw + (size_t)(bn + srow) * K + scol;
    u16* lA0 = &As[(size_t)tid * 8];
    u16* lA1 = &As[(size_t)(tid + 256) * 8];
    u16* lB0 = &Bs[(size_t)tid * 8];

    for (int k0 = 0; k0 < K; k0 += 32) {
        __syncthreads();
        gl_lds16(gA0 + k0, lA0);
        gl_lds16(gA1 + k0, lA1);
        gl_lds16(gB0 + k0, lB0);
        __syncthreads();
        bf16x8 af[2], bfr[4];
        #pragma unroll
        for (int i = 0; i < 2; i++) af[i]  = *(const bf16x8*)&As[(wm + i * 16 + l16) * 32 + quad * 8];
        #pragma unroll
        for (int j = 0; j < 4; j++) bfr[j] = *(const bf16x8*)&Bs[(j * 16 + l16) * 32 + quad * 8];
        #pragma unroll
        for (int i = 0; i < 2; i++)
            #pragma unroll
            for (int j = 0; j < 4; j++)
                acc[i][j] = __builtin_amdgcn_mfma_f32_16x16x32_bf16(af[i], bfr[j], acc[i][j], 0, 0, 0);
    }

    #pragma unroll
    for (int i = 0; i < 2; i++)
        #pragma unroll
        for (int j = 0; j < 4; j++)
            #pragma unroll
            for (int r = 0; r < 4; r++) {
                int mr = bm + wm + i * 16 + quad * 4 + r;
                int nc = bn + j * 16 + l16;
                C[(size_t)mr * 1024 + nc] = acc[i][j][r];
            }
}

// ---------- Flash attention: paired q-tiles, double-buffered LDS K/V ----------
// 1D grid 512. XCD swizzle: bh = (bid&7)*4 + (bid>>7) keeps each bh's 16 blocks
// on one XCD's L2 (4 bh x 512 KB = 2 MB). j = (bid>>3)&15. Q pre-scaled by CSC
// in rope, so exp2 applies directly to QK output. Fixed-max softmax (|s|<0.2).
__global__ __launch_bounds__(256, 2) void attn_kernel(const u16* __restrict__ Q,
                                                      const u16* __restrict__ Kb,
                                                      const u16* __restrict__ Vt,
                                                      u16* __restrict__ Oout) {
    __shared__ __align__(16) u16 KV[2][8192];    // per buf: Klo|Khi|Vlo|Vhi, 2048 u16 each
    __shared__ __align__(16) u16 PW[4 * 1152];   // per-wave P: 16 rows x 72 u16
    const int tid  = threadIdx.x;
    const int wave = tid >> 6, lane = tid & 63;
    const int l16  = lane & 15, quad = lane >> 4;
    const int bid  = blockIdx.x;
    const int j    = (bid >> 3) & 15;
    const int bh   = (bid & 7) * 4 + (bid >> 7);
    const int T    = 32 - j;                     // staged key tiles 0..T-1
    const int qA0  = j * 64 + wave * 16;
    const int qB0  = (31 - j) * 64 + wave * 16;

    const u16* Qh = Q  + (size_t)bh * 2048 * 64;
    const u16* Kh = Kb + (size_t)bh * 2048 * 64;
    const u16* Vh = Vt + (size_t)bh * 64 * 2048;

    bf16x8 qAf0 = *(const bf16x8*)&Qh[(size_t)(qA0 + l16) * 64 + quad * 8];
    bf16x8 qAf1 = *(const bf16x8*)&Qh[(size_t)(qA0 + l16) * 64 + 32 + quad * 8];
    bf16x8 qBf0 = *(const bf16x8*)&Qh[(size_t)(qB0 + l16) * 64 + quad * 8];
    bf16x8 qBf1 = *(const bf16x8*)&Qh[(size_t)(qB0 + l16) * 64 + 32 + quad * 8];

    f32x4 oA[4], oB[4];
    float lsA[4], lsB[4];
    #pragma unroll
    for (int t = 0; t < 4; t++)
        #pragma unroll
        for (int e = 0; e < 4; e++) { oA[t][e] = 0.0f; oB[t][e] = 0.0f; }
    #pragma unroll
    for (int r = 0; r < 4; r++) { lsA[r] = 0.0f; lsB[r] = 0.0f; }

    const u16* gK = Kh + (size_t)(tid >> 2) * 64 + (tid & 3) * 8;
    const u16* gV = Vh + (size_t)(tid >> 2) * 2048 + (tid & 3) * 8;

    u16* pw16 = PW + wave * 1152;
    u32* pw32 = (u32*)pw16;

    auto stage = [&](int t, int buf) {
        u16* base = KV[buf];
        gl_lds16(gK + (size_t)t * 4096,      base + (size_t)tid * 8);
        gl_lds16(gK + (size_t)t * 4096 + 32, base + 2048 + (size_t)tid * 8);
        gl_lds16(gV + (size_t)t * 64,        base + 4096 + (size_t)tid * 8);
        gl_lds16(gV + (size_t)t * 64 + 32,   base + 6144 + (size_t)tid * 8);
    };

    auto side = [&](const bf16x8& q0f, const bf16x8& q1f, bf16x8* kf0, bf16x8* kf1,
                    bf16x8* vf0, bf16x8* vf1, f32x4* o, float* ls,
                    int q0, int kbase, bool diag) {
        f32x4 s[4];
        #pragma unroll
        for (int n = 0; n < 4; n++) {
            #pragma unroll
            for (int e = 0; e < 4; e++) s[n][e] = 0.0f;
            s[n] = __builtin_amdgcn_mfma_f32_16x16x32_bf16(q0f, kf0[n], s[n], 0, 0, 0);
            s[n] = __builtin_amdgcn_mfma_f32_16x16x32_bf16(q1f, kf1[n], s[n], 0, 0, 0);
        }
        float p[4][4];
        #pragma unroll
        for (int n = 0; n < 4; n++)
            #pragma unroll
            for (int r = 0; r < 4; r++) {
                float v = exp2_fast(s[n][r]);        // q pre-scaled: s already *CSC
                if (diag) {
                    int row = q0 + quad * 4 + r;
                    v = (kbase + n * 16 + l16 > row) ? 0.0f : v;
                }
                p[n][r] = v;
                ls[r] += v;
            }
        #pragma unroll
        for (int c = 0; c < 2; c++)
            #pragma unroll
            for (int r = 0; r < 4; r++)
                pw32[(quad * 4 + r) * 36 + c * 16 + l16] =
                    (u32)f2bf(p[2 * c][r]) | ((u32)f2bf(p[2 * c + 1][r]) << 16);
        asm volatile("s_waitcnt lgkmcnt(0)" ::: "memory");   // wave-local drain
        bf16x8 pf0 = *(const bf16x8*)&pw16[l16 * 72 + quad * 8];
        bf16x8 pf1 = *(const bf16x8*)&pw16[l16 * 72 + 32 + quad * 8];
        #pragma unroll
        for (int dn = 0; dn < 4; dn++) {
            o[dn] = __builtin_amdgcn_mfma_f32_16x16x32_bf16(pf0, vf0[dn], o[dn], 0, 0, 0);
            o[dn] = __builtin_amdgcn_mfma_f32_16x16x32_bf16(pf1, vf1[dn], o[dn], 0, 0, 0);
        }
    };

    stage(0, 0);
    for (int t = 0; t < T; ++t) {
        __syncthreads();              // drains vmcnt: buf[t&1] ready; buf[(t+1)&1] free
        if (t + 1 < T) stage(t + 1, (t + 1) & 1);
        const u16* B = KV[t & 1];
        bf16x8 kf0[4], kf1[4], vf0[4], vf1[4];
        #pragma unroll
        for (int n = 0; n < 4; n++) {
            int ri = (n * 16 + l16) * 32 + quad * 8;
            kf0[n] = *(const bf16x8*)&B[ri];
            kf1[n] = *(const bf16x8*)&B[2048 + ri];
            vf0[n] = *(const bf16x8*)&B[4096 + ri];
            vf1[n] = *(const bf16x8*)&B[6144 + ri];
        }
        const int kbase = t * 64;
        side(qBf0, qBf1, kf0, kf1, vf0, vf1, oB, lsB, qB0, kbase, t == T - 1);
        if (t <= j)
            side(qAf0, qAf1, kf0, kf1, vf0, vf1, oA, lsA, qA0, kbase, t == j);
    }

    #pragma unroll
    for (int off = 1; off < 16; off <<= 1)
        #pragma unroll
        for (int r = 0; r < 4; r++) {
            lsA[r] += __shfl_xor(lsA[r], off);
            lsB[r] += __shfl_xor(lsB[r], off);
        }

    const int b = bh >> 4, h = bh & 15;
    #pragma unroll
    for (int r = 0; r < 4; r++) {
        float iA = 1.0f / lsA[r];
        float iB = 1.0f / lsB[r];
        int sA = qA0 + quad * 4 + r;
        int sB = qB0 + quad * 4 + r;
        #pragma unroll
        for (int dn = 0; dn < 4; dn++) {
            int d = h * 64 + dn * 16 + l16;
            Oout[((size_t)b * 2048 + sA) * 1024 + d] = f2bf(oA[dn][r] * iA);
            Oout[((size_t)b * 2048 + sB) * 1024 + d] = f2bf(oB[dn][r] * iB);
        }
    }
}

extern "C" void kernel_launch(void* const* d_in, const int* in_sizes, int n_in,
                              void* d_out, int out_size, void* d_ws, size_t ws_size,
                              hipStream_t stream) {
    const float* x  = (const float*)d_in[0];
    const float* wq = (const float*)d_in[1];
    const float* wk = (const float*)d_in[2];
    const float* wv = (const float*)d_in[3];
    const float* wo = (const float*)d_in[4];
    float* out = (float*)d_out;

    const int M = 4096, D = 1024;
    u16* xb    = (u16*)d_ws;                      // [4096,1024]            8 MB
    u16* qkvw  = xb   + (size_t)M * D;            // wq|wk|wv bf16          6 MB
    u16* ow    = qkvw + (size_t)3 * D * D;        // wo bf16                2 MB
    u16* qkv   = ow   + (size_t)D * D;            // q | k | v^T            24 MB
    u16* qb    = qkv;
    u16* kb    = qkv + (size_t)M * D;
    u16* vtb   = qkv + (size_t)2 * M * D;
    u16* aob   = qkv + (size_t)3 * M * D;         // attn out bf16 [B,S,D]  8 MB

    cvt_all_kernel<<<8192, 256, 0, stream>>>(x, wq, wk, wv, wo, xb, qkvw, ow);

    dim3 gq(32, 24);                               // 768 blocks = 3/CU
    gemm_qkv<<<gq, 256, 0, stream>>>(xb, qkvw, qkv, D);

    dim3 gr(2048, 2);                              // b128 rope; q pre-scaled by CSC
    rope_kernel<<<gr, 256, 0, stream>>>(qb, kb);

    attn_kernel<<<512, 256, 0, stream>>>(qb, kb, vtb, aob);

    dim3 go(32, 16);                               // 512 blocks, 128x64 tiles
    gemm_out<<<go, 256, 0, stream>>>(aob, ow, out, D);
}